// Round 1
// baseline (1539.075 us; speedup 1.0000x reference)
//
#include <hip/hip_runtime.h>
#include <hip/hip_bf16.h>
#include <stdint.h>
#include <stddef.h>

#define OUT_F  11008
#define IN_F   4096
#define M_ROWS 8192

typedef __bf16 bf16;
typedef __attribute__((ext_vector_type(8))) __bf16 bf16x8;
typedef __attribute__((ext_vector_type(4))) float floatx4;

__device__ const float NF4_TAB[16] = {
    -1.0f, -0.6961928009986877f, -0.5250730514526367f, -0.39491748809814453f,
    -0.28444138169288635f, -0.18477343022823334f, -0.09105003625154495f, 0.0f,
    0.07958029955625534f, 0.16093020141124725f, 0.24611230194568634f,
    0.33791524171829224f, 0.44070982933044434f, 0.5626170039176941f,
    0.7229568362236023f, 1.0f};

// ---------------------------------------------------------------- cvt x: fp32 -> bf16
__global__ __launch_bounds__(256) void cvt_x_kernel(const float* __restrict__ x,
                                                    bf16* __restrict__ xb) {
    size_t t = (size_t)blockIdx.x * 256 + threadIdx.x;   // 8 elements per thread
    const float4* xv = (const float4*)x;
    float4 a = xv[2 * t];
    float4 b = xv[2 * t + 1];
    bf16x8 o;
    o[0] = (bf16)a.x; o[1] = (bf16)a.y; o[2] = (bf16)a.z; o[3] = (bf16)a.w;
    o[4] = (bf16)b.x; o[5] = (bf16)b.y; o[6] = (bf16)b.z; o[7] = (bf16)b.w;
    *(bf16x8*)(xb + 8 * t) = o;
}

// ------------------------------------------------- dequant: NF4 idx * scale -> bf16 W
__global__ __launch_bounds__(256) void dequant_kernel(const int* __restrict__ q,
                                                      const float* __restrict__ sc,
                                                      bf16* __restrict__ wb) {
    __shared__ float tab[16];
    if (threadIdx.x < 16) tab[threadIdx.x] = NF4_TAB[threadIdx.x];
    __syncthreads();
    size_t t = (size_t)blockIdx.x * 256 + threadIdx.x;   // 8 elements per thread
    const int4* qv = (const int4*)q;
    int4 a = qv[2 * t];
    int4 b = qv[2 * t + 1];
    float s = sc[t >> 4];   // group = (8t)/128 = t/16 ; 8t%128 <= 120 so uniform over 8
    bf16x8 o;
    o[0] = (bf16)(tab[a.x & 15] * s); o[1] = (bf16)(tab[a.y & 15] * s);
    o[2] = (bf16)(tab[a.z & 15] * s); o[3] = (bf16)(tab[a.w & 15] * s);
    o[4] = (bf16)(tab[b.x & 15] * s); o[5] = (bf16)(tab[b.y & 15] * s);
    o[6] = (bf16)(tab[b.z & 15] * s); o[7] = (bf16)(tab[b.w & 15] * s);
    *(bf16x8*)(wb + 8 * t) = o;
}

// ---------------------------------------------------------------- MFMA GEMM + bias
// C[M,N] = A[M,K] * B[N,K]^T + bias.  256x256 tile, BK=32, 8 waves (2Mx4N),
// 4-deep LDS ring buffer, counted vmcnt (never 0 in main loop), 1 barrier/K-tile,
// XOR-swizzled LDS (slot ^= row&3; pre-swizzled global source, global_load_lds
// keeps linear dest), s_setprio around MFMA clusters, XCD-aware block swizzle.
//
// Pipeline hazards (4 buffers, prefetch distance 3, all ref to K-tile index t):
//  RAW: tile t staged at iter t-3; vmcnt(8) at top of iter t retires everything
//       older than the 8 youngest loads (= tiles t+1,t+2) -> tile t landed;
//       barrier publishes all waves' DMAs before any ds_read.
//  WAR: buf[t&3] is next written by tile t+4, issued after the top-of-iter-(t+1)
//       barrier; every wave's last ds_read of tile t precedes that barrier.
//  WAW: same wave re-stages a buffer only after its own vmcnt(8) retired the
//       previous tenant's loads.
#define BM 256
#define BN 256
#define BK 32
#define NT (IN_F / BK)                 // 128 K-tiles
#define GRID ((M_ROWS / BM) * (OUT_F / BN))   // 32*43 = 1376, % 8 == 0

static __device__ __forceinline__ void gload_lds16(const void* g, void* l) {
    __builtin_amdgcn_global_load_lds((const __attribute__((address_space(1))) void*)g,
                                     (__attribute__((address_space(3))) void*)l,
                                     16, 0, 0);
}

__global__ __launch_bounds__(512, 2) void gemm_bias_kernel(const bf16* __restrict__ A,
                                                           const bf16* __restrict__ B,
                                                           const float* __restrict__ bias,
                                                           float* __restrict__ C) {
    __shared__ bf16 sA[4][BM * BK];   // 4 x 16 KB
    __shared__ bf16 sB[4][BN * BK];   // 4 x 16 KB  -> 128 KB total

    const int tid  = threadIdx.x;
    const int w    = tid >> 6;        // wave 0..7
    const int lane = tid & 63;
    const int wm   = w >> 2;          // 0..1  (wave owns 128 rows)
    const int wn   = w & 3;           // 0..3  (wave owns 64 cols)
    const int l16  = lane & 15;
    const int quad = lane >> 4;

    // XCD-aware bijective swizzle (grid % 8 == 0): each XCD gets a contiguous
    // chunk of 172 tiles = 4 full tile-rows -> A panels stay hot in its L2.
    const int bid = blockIdx.x;
    const int swz = (bid & 7) * (GRID / 8) + (bid >> 3);
    const int tm  = swz / (OUT_F / BN);
    const int tn  = swz % (OUT_F / BN);
    const int bm  = tm * BM;
    const int bn  = tn * BN;

    // ---- staging: wave w covers 32 rows of A and of B per K-tile, 2 issues each
    // (issue = 64 lanes x 16B = 16 rows of 64B). LDS dest is linear (DMA rule);
    // the XOR swizzle is applied by permuting the per-lane GLOBAL source slot.
    const int lr = lane >> 2;                 // row within 16-row chunk
    const int ls = (lane & 3) ^ (lr & 3);     // logical 16B slot (inverse swizzle)
    const bf16* aG = A + (size_t)(bm + w * 32 + lr) * IN_F + ls * 8;
    const bf16* bG = B + (size_t)(bn + w * 32 + lr) * IN_F + ls * 8;

    // ---- fragment ds_read offsets (elements). Physical slot = quad ^ (row&3).
    const int soff = (quad ^ (l16 & 3)) * 8;
    const int aOff = (wm * 128 + l16) * BK + soff;
    const int bOff = (wn * 64 + l16) * BK + soff;

    floatx4 acc[8][4] = {};

    auto stage = [&](int tt) {
        bf16* la = &sA[tt & 3][w * 1024];
        bf16* lb = &sB[tt & 3][w * 1024];
        const bf16* ga = aG + (size_t)tt * BK;
        const bf16* gb = bG + (size_t)tt * BK;
        gload_lds16(ga, la);
        gload_lds16(ga + (size_t)16 * IN_F, la + 512);
        gload_lds16(gb, lb);
        gload_lds16(gb + (size_t)16 * IN_F, lb + 512);
    };

    auto compute = [&](int t) {
        const bf16* bufA = sA[t & 3];
        const bf16* bufB = sB[t & 3];
        bf16x8 bfrg[4], afrg[4];
#pragma unroll
        for (int nt = 0; nt < 4; ++nt)
            bfrg[nt] = *(const bf16x8*)(bufB + bOff + nt * 512);
#pragma unroll
        for (int mt = 0; mt < 4; ++mt)
            afrg[mt] = *(const bf16x8*)(bufA + aOff + mt * 512);
        asm volatile("s_waitcnt lgkmcnt(0)" ::: "memory");
        __builtin_amdgcn_s_setprio(1);
#pragma unroll
        for (int mt = 0; mt < 4; ++mt)
#pragma unroll
            for (int nt = 0; nt < 4; ++nt)
                acc[mt][nt] = __builtin_amdgcn_mfma_f32_16x16x32_bf16(
                    afrg[mt], bfrg[nt], acc[mt][nt], 0, 0, 0);
        __builtin_amdgcn_s_setprio(0);
#pragma unroll
        for (int mt = 0; mt < 4; ++mt)
            afrg[mt] = *(const bf16x8*)(bufA + aOff + (mt + 4) * 512);
        asm volatile("s_waitcnt lgkmcnt(0)" ::: "memory");
        __builtin_amdgcn_s_setprio(1);
#pragma unroll
        for (int mt = 0; mt < 4; ++mt)
#pragma unroll
            for (int nt = 0; nt < 4; ++nt)
                acc[mt + 4][nt] = __builtin_amdgcn_mfma_f32_16x16x32_bf16(
                    afrg[mt], bfrg[nt], acc[mt + 4][nt], 0, 0, 0);
        __builtin_amdgcn_s_setprio(0);
    };

    // prologue: fill 3 of the 4 ring slots
    stage(0); stage(1); stage(2);

    for (int t = 0; t < NT - 3; ++t) {
        asm volatile("s_waitcnt vmcnt(8)" ::: "memory");   // tile t landed (own wave)
        __builtin_amdgcn_s_barrier();                      // all waves' DMAs + WAR fence
        stage(t + 3);
        compute(t);
    }
    asm volatile("s_waitcnt vmcnt(8)" ::: "memory");
    __builtin_amdgcn_s_barrier();
    compute(NT - 3);
    asm volatile("s_waitcnt vmcnt(4)" ::: "memory");
    __builtin_amdgcn_s_barrier();
    compute(NT - 2);
    asm volatile("s_waitcnt vmcnt(0)" ::: "memory");
    __builtin_amdgcn_s_barrier();
    compute(NT - 1);

    // epilogue: C/D layout col=lane&15, row=quad*4+reg  [m89-verified]
#pragma unroll
    for (int nt = 0; nt < 4; ++nt) {
        int col = bn + wn * 64 + nt * 16 + l16;
        float bv = bias[col];
#pragma unroll
        for (int mt = 0; mt < 8; ++mt) {
            int row0 = bm + wm * 128 + mt * 16 + quad * 4;
#pragma unroll
            for (int r = 0; r < 4; ++r)
                C[(size_t)(row0 + r) * OUT_F + col] = acc[mt][nt][r] + bv;
        }
    }
}

// ------------------------------------- fallback (no workspace): fp32 tiled GEMM
#define FBM 64
#define FBN 64
#define FBK 64
__global__ __launch_bounds__(256) void fallback_gemm(const float* __restrict__ x,
                                                     const int* __restrict__ q,
                                                     const float* __restrict__ sc,
                                                     const float* __restrict__ bias,
                                                     float* __restrict__ out) {
    __shared__ float sA[FBM][FBK + 1];
    __shared__ float sB[FBN][FBK + 1];
    const int tx = threadIdx.x & 15, ty = threadIdx.x >> 4;
    const int bm = blockIdx.y * FBM, bn = blockIdx.x * FBN;
    float acc[4][4] = {};
    for (int k0 = 0; k0 < IN_F; k0 += FBK) {
        for (int i = threadIdx.x; i < FBM * (FBK / 4); i += 256) {
            int r = i / (FBK / 4), c4 = (i % (FBK / 4)) * 4;
            float4 v = *(const float4*)&x[(size_t)(bm + r) * IN_F + k0 + c4];
            sA[r][c4] = v.x; sA[r][c4 + 1] = v.y; sA[r][c4 + 2] = v.z; sA[r][c4 + 3] = v.w;
            size_t fi = (size_t)(bn + r) * IN_F + k0 + c4;
            int4 qv = *(const int4*)&q[fi];
            float s = sc[fi >> 7];
            sB[r][c4]     = NF4_TAB[qv.x & 15] * s;
            sB[r][c4 + 1] = NF4_TAB[qv.y & 15] * s;
            sB[r][c4 + 2] = NF4_TAB[qv.z & 15] * s;
            sB[r][c4 + 3] = NF4_TAB[qv.w & 15] * s;
        }
        __syncthreads();
        for (int k = 0; k < FBK; ++k) {
            float av[4], bvv[4];
#pragma unroll
            for (int i = 0; i < 4; ++i) av[i] = sA[ty * 4 + i][k];
#pragma unroll
            for (int j = 0; j < 4; ++j) bvv[j] = sB[tx * 4 + j][k];
#pragma unroll
            for (int i = 0; i < 4; ++i)
#pragma unroll
                for (int j = 0; j < 4; ++j) acc[i][j] += av[i] * bvv[j];
        }
        __syncthreads();
    }
#pragma unroll
    for (int i = 0; i < 4; ++i)
#pragma unroll
        for (int j = 0; j < 4; ++j)
            out[(size_t)(bm + ty * 4 + i) * OUT_F + bn + tx * 4 + j] =
                acc[i][j] + bias[bn + tx * 4 + j];
}

// ---------------------------------------------------------------- launch
extern "C" void kernel_launch(void* const* d_in, const int* in_sizes, int n_in,
                              void* d_out, int out_size, void* d_ws, size_t ws_size,
                              hipStream_t stream) {
    const float* x    = (const float*)d_in[0];
    const int*   q    = (const int*)d_in[1];
    const float* sc   = (const float*)d_in[2];
    const float* bias = (const float*)d_in[3];
    float* out = (float*)d_out;

    const size_t xb_bytes = (size_t)M_ROWS * IN_F * sizeof(bf16);   // 67.1 MB
    const size_t wb_bytes = (size_t)OUT_F * IN_F * sizeof(bf16);    // 90.2 MB

    if (ws_size >= xb_bytes + wb_bytes) {
        bf16* xb = (bf16*)d_ws;
        bf16* wb = (bf16*)((char*)d_ws + xb_bytes);
        cvt_x_kernel<<<(M_ROWS * IN_F) / (8 * 256), 256, 0, stream>>>(x, xb);
        dequant_kernel<<<(OUT_F * IN_F) / (8 * 256), 256, 0, stream>>>(q, sc, wb);
        gemm_bias_kernel<<<GRID, 512, 0, stream>>>(xb, wb, bias, out);
    } else {
        fallback_gemm<<<dim3(OUT_F / FBN, M_ROWS / FBM), 256, 0, stream>>>(x, q, sc, bias, out);
    }
}

// Round 2
// 1426.520 us; speedup vs baseline: 1.0789x; 1.0789x over previous
//
#include <hip/hip_runtime.h>
#include <hip/hip_bf16.h>
#include <stdint.h>
#include <stddef.h>

#define OUT_F  11008
#define IN_F   4096
#define M_ROWS 8192

typedef __bf16 bf16;
typedef __attribute__((ext_vector_type(8))) __bf16 bf16x8;
typedef __attribute__((ext_vector_type(4))) float floatx4;

__device__ const float NF4_TAB[16] = {
    -1.0f, -0.6961928009986877f, -0.5250730514526367f, -0.39491748809814453f,
    -0.28444138169288635f, -0.18477343022823334f, -0.09105003625154495f, 0.0f,
    0.07958029955625534f, 0.16093020141124725f, 0.24611230194568634f,
    0.33791524171829224f, 0.44070982933044434f, 0.5626170039176941f,
    0.7229568362236023f, 1.0f};

// ---------------------------------------------------------------- cvt x: fp32 -> bf16
__global__ __launch_bounds__(256) void cvt_x_kernel(const float* __restrict__ x,
                                                    bf16* __restrict__ xb) {
    size_t t = (size_t)blockIdx.x * 256 + threadIdx.x;   // 8 elements per thread
    const float4* xv = (const float4*)x;
    float4 a = xv[2 * t];
    float4 b = xv[2 * t + 1];
    bf16x8 o;
    o[0] = (bf16)a.x; o[1] = (bf16)a.y; o[2] = (bf16)a.z; o[3] = (bf16)a.w;
    o[4] = (bf16)b.x; o[5] = (bf16)b.y; o[6] = (bf16)b.z; o[7] = (bf16)b.w;
    *(bf16x8*)(xb + 8 * t) = o;
}

// ------------------------------------------------- dequant: NF4 idx * scale -> bf16 W
__global__ __launch_bounds__(256) void dequant_kernel(const int* __restrict__ q,
                                                      const float* __restrict__ sc,
                                                      bf16* __restrict__ wb) {
    __shared__ float tab[16];
    if (threadIdx.x < 16) tab[threadIdx.x] = NF4_TAB[threadIdx.x];
    __syncthreads();
    size_t t = (size_t)blockIdx.x * 256 + threadIdx.x;   // 8 elements per thread
    const int4* qv = (const int4*)q;
    int4 a = qv[2 * t];
    int4 b = qv[2 * t + 1];
    float s = sc[t >> 4];
    bf16x8 o;
    o[0] = (bf16)(tab[a.x & 15] * s); o[1] = (bf16)(tab[a.y & 15] * s);
    o[2] = (bf16)(tab[a.z & 15] * s); o[3] = (bf16)(tab[a.w & 15] * s);
    o[4] = (bf16)(tab[b.x & 15] * s); o[5] = (bf16)(tab[b.y & 15] * s);
    o[6] = (bf16)(tab[b.z & 15] * s); o[7] = (bf16)(tab[b.w & 15] * s);
    *(bf16x8*)(wb + 8 * t) = o;
}

// ---------------------------------------------------------------- MFMA GEMM + bias
// m201-style 256x256 8-phase schedule, BK=64, 8 waves (2Mx4N), double-buffered
// [128][64] bf16 LDS halves with st_16x32 swizzle (byte ^= ((byte>>9)&1)<<5),
// linear global_load_lds dest + pre-swizzled per-lane GLOBAL source + swizzled
// ds_read (both-sides involution).  Per K-tile: 4 phases, each = {ds_read one
// quadrant's frags, stage, barrier, lgkm0+schedbar, setprio, 16 MFMA, barrier}.
// Tile T+1 staged in ph1/ph2 of tile T; single vmcnt(0) at end of ph4 (~700 cy
// after last issue, so the drain is mostly hidden).
#define BM 256
#define BN 256
#define BK 64
#define NT (IN_F / BK)                        // 64 K-tiles
#define GRID ((M_ROWS / BM) * (OUT_F / BN))   // 32*43 = 1376, % 8 == 0

static __device__ __forceinline__ void gload_lds16(const void* g, void* l) {
    __builtin_amdgcn_global_load_lds((const __attribute__((address_space(1))) void*)g,
                                     (__attribute__((address_space(3))) void*)l,
                                     16, 0, 0);
}

__global__ __launch_bounds__(512, 2) void gemm_bias_kernel(const bf16* __restrict__ A,
                                                           const bf16* __restrict__ B,
                                                           const float* __restrict__ bias,
                                                           float* __restrict__ C) {
    // [dbuf][half][128 rows x 64 cols]  -> 16 KB each, 128 KB total
    __shared__ bf16 sA[2][2][8192];
    __shared__ bf16 sB[2][2][8192];

    const int tid  = threadIdx.x;
    const int w    = tid >> 6;        // wave 0..7
    const int lane = tid & 63;
    const int wm   = w >> 2;          // 0..1 : wave's 128-row A half
    const int wn   = w & 3;           // 0..3 : wave's 64-col slice of B
    const int l16  = lane & 15;
    const int quad = lane >> 4;

    // XCD-aware bijective swizzle (GRID % 8 == 0)
    const int bid = blockIdx.x;
    const int swz = (bid & 7) * (GRID / 8) + (bid >> 3);
    const int tm  = swz / (OUT_F / BN);
    const int tn  = swz % (OUT_F / BN);
    const int bm  = tm * BM;
    const int bn  = tn * BN;

    // ---- staging source (pre-swizzled): phys LDS byte p -> logical l = p ^ bit9>>bit5
    // wave writes 2 KB per half-tile: p = w*2048 + i*1024 + lane*16
    const int p0   = w * 2048 + lane * 16;
    const int l0   = p0 ^ (((p0 >> 9) & 1) << 5);
    const int srow = l0 >> 7;          // 0..127 (row within half)
    const int scol = (l0 & 127) >> 1;  // bf16 col 0..63
    const bf16* aSrc = A + (size_t)(bm + srow) * IN_F + scol;
    const bf16* bSrc = B + (size_t)(bn + srow) * IN_F + scol;

    auto stage = [&](int ts, int hf) {   // hf: 0=A half0, 1=B half0, 2=A half1, 3=B half1
        const int c    = ts & 1;
        const int half = hf >> 1;
        const bf16* src = (hf & 1) ? bSrc : aSrc;
        bf16* dst = (hf & 1) ? &sB[c][half][0] : &sA[c][half][0];
        const bf16* s0 = src + (size_t)(half * 128) * IN_F + (size_t)ts * BK;
        gload_lds16(s0, dst + w * 1024);
        gload_lds16(s0 + (size_t)8 * IN_F, dst + w * 1024 + 512);
    };

    // ---- swizzled fragment read offsets (bytes).  logical = row*128 + ks*64 + quad*16,
    // bit9(logical) = row bit2 = (l16>>2)&1  ->  xr applies to the final byte addr.
    const int xr = ((l16 >> 2) & 1) << 5;
    const int tA = (l16 * 128 + quad * 16) ^ xr;                     // + f*2048 + ks*64
    const int tB = ((wn & 1) * 8192 + l16 * 128 + quad * 16) ^ xr;   // + f*2048 + ks*64

    floatx4 acc[8][4] = {};
    bf16x8 af[4][2];    // current A subtile: 4 mfrags x 2 ks
    bf16x8 b01[2][2];   // B nf0-1
    bf16x8 b23[2][2];   // B nf2-3

#define RD_A(c, f, ks) (*(const bf16x8*)((const char*)&sA[c][wm][0] + tA + (f) * 2048 + (ks) * 64))
#define RD_B(c, f, ks) (*(const bf16x8*)((const char*)&sB[c][wn >> 1][0] + tB + (f) * 2048 + (ks) * 64))

#define QUADRANT(MB, BV, NB)                                                     \
    do {                                                                         \
        _Pragma("unroll") for (int ks = 0; ks < 2; ++ks)                         \
        _Pragma("unroll") for (int mf = 0; mf < 4; ++mf)                         \
        _Pragma("unroll") for (int nf = 0; nf < 2; ++nf)                         \
            acc[(MB) + mf][(NB) + nf] = __builtin_amdgcn_mfma_f32_16x16x32_bf16( \
                af[mf][ks], BV[nf][ks], acc[(MB) + mf][(NB) + nf], 0, 0, 0);     \
    } while (0)

#define PHASE_SYNC()                                  \
    __builtin_amdgcn_s_barrier();                     \
    asm volatile("s_waitcnt lgkmcnt(0)");             \
    __builtin_amdgcn_sched_barrier(0)

    // prologue: stage K-tile 0, drain once
    stage(0, 0); stage(0, 1); stage(0, 2); stage(0, 3);
    asm volatile("s_waitcnt vmcnt(0)" ::: "memory");
    __builtin_amdgcn_s_barrier();

    for (int T = 0; T < NT; ++T) {
        const int cur = T & 1;
        const bool pf = (T + 1 < NT);

        // ---- phase 1: A mf0-3 (8 reads) + B nf0-1 (4 reads); stage A0,B0 of T+1
#pragma unroll
        for (int f = 0; f < 4; ++f) { af[f][0] = RD_A(cur, f, 0); af[f][1] = RD_A(cur, f, 1); }
#pragma unroll
        for (int f = 0; f < 2; ++f) { b01[f][0] = RD_B(cur, f, 0); b01[f][1] = RD_B(cur, f, 1); }
        if (pf) { stage(T + 1, 0); stage(T + 1, 1); }
        PHASE_SYNC();
        __builtin_amdgcn_s_setprio(1);
        QUADRANT(0, b01, 0);
        __builtin_amdgcn_s_setprio(0);
        __builtin_amdgcn_s_barrier();

        // ---- phase 2: B nf2-3 (4 reads); stage A1,B1 of T+1
#pragma unroll
        for (int f = 0; f < 2; ++f) { b23[f][0] = RD_B(cur, f + 2, 0); b23[f][1] = RD_B(cur, f + 2, 1); }
        if (pf) { stage(T + 1, 2); stage(T + 1, 3); }
        PHASE_SYNC();
        __builtin_amdgcn_s_setprio(1);
        QUADRANT(0, b23, 2);
        __builtin_amdgcn_s_setprio(0);
        __builtin_amdgcn_s_barrier();

        // ---- phase 3: A mf4-7 (8 reads, overwrite af)
#pragma unroll
        for (int f = 0; f < 4; ++f) { af[f][0] = RD_A(cur, f + 4, 0); af[f][1] = RD_A(cur, f + 4, 1); }
        PHASE_SYNC();
        __builtin_amdgcn_s_setprio(1);
        QUADRANT(4, b23, 2);
        __builtin_amdgcn_s_setprio(0);
        __builtin_amdgcn_s_barrier();

        // ---- phase 4: B nf0-1 re-read (4 reads, saves 16 VGPR); tile-boundary vmcnt
#pragma unroll
        for (int f = 0; f < 2; ++f) { b01[f][0] = RD_B(cur, f, 0); b01[f][1] = RD_B(cur, f, 1); }
        PHASE_SYNC();
        __builtin_amdgcn_s_setprio(1);
        QUADRANT(4, b01, 0);
        __builtin_amdgcn_s_setprio(0);
        if (pf) asm volatile("s_waitcnt vmcnt(0)" ::: "memory");   // T+1 staged in ph1/ph2
        __builtin_amdgcn_s_barrier();
    }

    // epilogue: C/D layout col=lane&15, row=quad*4+reg  [m89-verified]
#pragma unroll
    for (int nt = 0; nt < 4; ++nt) {
        int col = bn + wn * 64 + nt * 16 + l16;
        float bv = bias[col];
#pragma unroll
        for (int mt = 0; mt < 8; ++mt) {
            int row0 = bm + wm * 128 + mt * 16 + quad * 4;
#pragma unroll
            for (int r = 0; r < 4; ++r)
                C[(size_t)(row0 + r) * OUT_F + col] = acc[mt][nt][r] + bv;
        }
    }
#undef RD_A
#undef RD_B
#undef QUADRANT
#undef PHASE_SYNC
}

// ------------------------------------- fallback (no workspace): fp32 tiled GEMM
#define FBM 64
#define FBN 64
#define FBK 64
__global__ __launch_bounds__(256) void fallback_gemm(const float* __restrict__ x,
                                                     const int* __restrict__ q,
                                                     const float* __restrict__ sc,
                                                     const float* __restrict__ bias,
                                                     float* __restrict__ out) {
    __shared__ float sA[FBM][FBK + 1];
    __shared__ float sB[FBN][FBK + 1];
    const int tx = threadIdx.x & 15, ty = threadIdx.x >> 4;
    const int bm = blockIdx.y * FBM, bn = blockIdx.x * FBN;
    float acc[4][4] = {};
    for (int k0 = 0; k0 < IN_F; k0 += FBK) {
        for (int i = threadIdx.x; i < FBM * (FBK / 4); i += 256) {
            int r = i / (FBK / 4), c4 = (i % (FBK / 4)) * 4;
            float4 v = *(const float4*)&x[(size_t)(bm + r) * IN_F + k0 + c4];
            sA[r][c4] = v.x; sA[r][c4 + 1] = v.y; sA[r][c4 + 2] = v.z; sA[r][c4 + 3] = v.w;
            size_t fi = (size_t)(bn + r) * IN_F + k0 + c4;
            int4 qv = *(const int4*)&q[fi];
            float s = sc[fi >> 7];
            sB[r][c4]     = NF4_TAB[qv.x & 15] * s;
            sB[r][c4 + 1] = NF4_TAB[qv.y & 15] * s;
            sB[r][c4 + 2] = NF4_TAB[qv.z & 15] * s;
            sB[r][c4 + 3] = NF4_TAB[qv.w & 15] * s;
        }
        __syncthreads();
        for (int k = 0; k < FBK; ++k) {
            float av[4], bvv[4];
#pragma unroll
            for (int i = 0; i < 4; ++i) av[i] = sA[ty * 4 + i][k];
#pragma unroll
            for (int j = 0; j < 4; ++j) bvv[j] = sB[tx * 4 + j][k];
#pragma unroll
            for (int i = 0; i < 4; ++i)
#pragma unroll
                for (int j = 0; j < 4; ++j) acc[i][j] += av[i] * bvv[j];
        }
        __syncthreads();
    }
#pragma unroll
    for (int i = 0; i < 4; ++i)
#pragma unroll
        for (int j = 0; j < 4; ++j)
            out[(size_t)(bm + ty * 4 + i) * OUT_F + bn + tx * 4 + j] =
                acc[i][j] + bias[bn + tx * 4 + j];
}

// ---------------------------------------------------------------- launch
extern "C" void kernel_launch(void* const* d_in, const int* in_sizes, int n_in,
                              void* d_out, int out_size, void* d_ws, size_t ws_size,
                              hipStream_t stream) {
    const float* x    = (const float*)d_in[0];
    const int*   q    = (const int*)d_in[1];
    const float* sc   = (const float*)d_in[2];
    const float* bias = (const float*)d_in[3];
    float* out = (float*)d_out;

    const size_t xb_bytes = (size_t)M_ROWS * IN_F * sizeof(bf16);   // 67.1 MB
    const size_t wb_bytes = (size_t)OUT_F * IN_F * sizeof(bf16);    // 90.2 MB

    if (ws_size >= xb_bytes + wb_bytes) {
        bf16* xb = (bf16*)d_ws;
        bf16* wb = (bf16*)((char*)d_ws + xb_bytes);
        cvt_x_kernel<<<(M_ROWS * IN_F) / (8 * 256), 256, 0, stream>>>(x, xb);
        dequant_kernel<<<(OUT_F * IN_F) / (8 * 256), 256, 0, stream>>>(q, sc, wb);
        gemm_bias_kernel<<<GRID, 512, 0, stream>>>(xb, wb, bias, out);
    } else {
        fallback_gemm<<<dim3(OUT_F / FBN, M_ROWS / FBM), 256, 0, stream>>>(x, q, sc, bias, out);
    }
}

// Round 3
// 1380.472 us; speedup vs baseline: 1.1149x; 1.0334x over previous
//
#include <hip/hip_runtime.h>
#include <hip/hip_bf16.h>
#include <stdint.h>
#include <stddef.h>

#define OUT_F  11008
#define IN_F   4096
#define M_ROWS 8192

typedef __bf16 bf16;
typedef __attribute__((ext_vector_type(8))) __bf16 bf16x8;
typedef __attribute__((ext_vector_type(4))) float floatx4;

__device__ const float NF4_TAB[16] = {
    -1.0f, -0.6961928009986877f, -0.5250730514526367f, -0.39491748809814453f,
    -0.28444138169288635f, -0.18477343022823334f, -0.09105003625154495f, 0.0f,
    0.07958029955625534f, 0.16093020141124725f, 0.24611230194568634f,
    0.33791524171829224f, 0.44070982933044434f, 0.5626170039176941f,
    0.7229568362236023f, 1.0f};

// ---------------------------------------------------------------- cvt x: fp32 -> bf16
__global__ __launch_bounds__(256) void cvt_x_kernel(const float* __restrict__ x,
                                                    bf16* __restrict__ xb) {
    size_t t = (size_t)blockIdx.x * 256 + threadIdx.x;   // 8 elements per thread
    const float4* xv = (const float4*)x;
    float4 a = xv[2 * t];
    float4 b = xv[2 * t + 1];
    bf16x8 o;
    o[0] = (bf16)a.x; o[1] = (bf16)a.y; o[2] = (bf16)a.z; o[3] = (bf16)a.w;
    o[4] = (bf16)b.x; o[5] = (bf16)b.y; o[6] = (bf16)b.z; o[7] = (bf16)b.w;
    *(bf16x8*)(xb + 8 * t) = o;
}

// ------------------------------------------------- dequant: NF4 idx * scale -> bf16 W
__global__ __launch_bounds__(256) void dequant_kernel(const int* __restrict__ q,
                                                      const float* __restrict__ sc,
                                                      bf16* __restrict__ wb) {
    __shared__ float tab[16];
    if (threadIdx.x < 16) tab[threadIdx.x] = NF4_TAB[threadIdx.x];
    __syncthreads();
    size_t t = (size_t)blockIdx.x * 256 + threadIdx.x;   // 8 elements per thread
    const int4* qv = (const int4*)q;
    int4 a = qv[2 * t];
    int4 b = qv[2 * t + 1];
    float s = sc[t >> 4];
    bf16x8 o;
    o[0] = (bf16)(tab[a.x & 15] * s); o[1] = (bf16)(tab[a.y & 15] * s);
    o[2] = (bf16)(tab[a.z & 15] * s); o[3] = (bf16)(tab[a.w & 15] * s);
    o[4] = (bf16)(tab[b.x & 15] * s); o[5] = (bf16)(tab[b.y & 15] * s);
    o[6] = (bf16)(tab[b.z & 15] * s); o[7] = (bf16)(tab[b.w & 15] * s);
    *(bf16x8*)(wb + 8 * t) = o;
}

// ---------------------------------------------------------------- MFMA GEMM + bias
// 256x256 tile, BK=64, 8 waves (2Mx4N), double-buffered [128][64] bf16 LDS halves.
// LDS swizzle (G4 recipe, both-sides involution, rule #21):
//   physical 16B-slot = logical slot ^ (row & 7)       (8 slots per 128 B row)
//   - write side: global_load_lds dest stays LINEAR; the per-lane GLOBAL source
//     column is inverse-permuted: src slot = (lane&7) ^ (lane>>3)
//     (row-within-16-row-chunk == lane>>3, so row&7 == lane>>3 exactly)
//   - read side: frag (row=l16+16f, k-slot=quad+4ks) reads phys slot
//     (quad+4ks)^(l16&7)  ==> byte = (tbase + f*2048) ^ (ks*64)
//   For fixed quad, rows 0..7 hit all 8 slots (XOR bijective) -> 2 lanes/bank: free.
// Per K-tile: 4 phases {ds_read quadrant frags | stage T+1 halves, barrier,
// lgkm0+schedbar, setprio, 16 MFMA, barrier}; single vmcnt(0) at end of ph4
// (~2 phases after last DMA issue).  b01 stays live all tile (no ph4 re-read;
// VGPR headroom: LDS caps us at 1 block/CU so up to 256 VGPR is free).
#define BM 256
#define BN 256
#define BK 64
#define NT (IN_F / BK)                        // 64 K-tiles
#define GRID ((M_ROWS / BM) * (OUT_F / BN))   // 32*43 = 1376, % 8 == 0

static __device__ __forceinline__ void gload_lds16(const void* g, void* l) {
    __builtin_amdgcn_global_load_lds((const __attribute__((address_space(1))) void*)g,
                                     (__attribute__((address_space(3))) void*)l,
                                     16, 0, 0);
}

__global__ __launch_bounds__(512, 2) void gemm_bias_kernel(const bf16* __restrict__ A,
                                                           const bf16* __restrict__ B,
                                                           const float* __restrict__ bias,
                                                           float* __restrict__ C) {
    // [dbuf][half][128 rows x 64 cols]  -> 16 KB each, 128 KB total
    __shared__ bf16 sA[2][2][8192];
    __shared__ bf16 sB[2][2][8192];

    const int tid  = threadIdx.x;
    const int w    = tid >> 6;        // wave 0..7
    const int lane = tid & 63;
    const int wm   = w >> 2;          // 0..1 : wave's 128-row A half
    const int wn   = w & 3;           // 0..3 : wave's 64-col slice of B
    const int l16  = lane & 15;
    const int quad = lane >> 4;

    // XCD-aware bijective swizzle (GRID % 8 == 0)
    const int bid = blockIdx.x;
    const int swz = (bid & 7) * (GRID / 8) + (bid >> 3);
    const int tm  = swz / (OUT_F / BN);
    const int tn  = swz % (OUT_F / BN);
    const int bm  = tm * BM;
    const int bn  = tn * BN;

    // ---- staging source (pre-swizzled).  Wave w writes phys bytes
    // [w*2048 + i*1024 + lane*16): row = w*16 + i*8 + (lane>>3), phys slot = lane&7.
    // Logical slot = phys ^ (row&7) = (lane&7) ^ (lane>>3)   (i*8, w*16 are 0 mod 8).
    const int srow = w * 16 + (lane >> 3);
    const int scol = ((lane & 7) ^ (lane >> 3)) * 8;
    const bf16* aSrc = A + (size_t)(bm + srow) * IN_F + scol;
    const bf16* bSrc = B + (size_t)(bn + srow) * IN_F + scol;

    auto stage = [&](int ts, int hf) {   // hf: 0=A half0, 1=B half0, 2=A half1, 3=B half1
        const int c    = ts & 1;
        const int half = hf >> 1;
        const bf16* src = (hf & 1) ? bSrc : aSrc;
        bf16* dst = (hf & 1) ? &sB[c][half][0] : &sA[c][half][0];
        const bf16* s0 = src + (size_t)(half * 128) * IN_F + (size_t)ts * BK;
        gload_lds16(s0, dst + w * 1024);                       // rows w*16 .. w*16+7
        gload_lds16(s0 + (size_t)8 * IN_F, dst + w * 1024 + 512);  // rows +8..+15
    };

    // ---- swizzled fragment read offsets (bytes): row l16 (+16 per frag),
    // phys slot = (quad + 4*ks) ^ (l16&7); ks toggles bit 6 (slot bit 2).
    const int sl = (quad ^ (l16 & 7)) * 16;
    const int tA = l16 * 128 + sl;
    const int tB = (wn & 1) * 8192 + l16 * 128 + sl;

    floatx4 acc[8][4] = {};
    bf16x8 af[4][2];    // current A subtile: 4 mfrags x 2 ks
    bf16x8 b01[2][2];   // B nf0-1 (live whole tile)
    bf16x8 b23[2][2];   // B nf2-3

#define RD_A(c, f, ks) \
    (*(const bf16x8*)((const char*)&sA[c][wm][0] + ((tA + (f) * 2048) ^ ((ks) * 64))))
#define RD_B(c, f, ks) \
    (*(const bf16x8*)((const char*)&sB[c][wn >> 1][0] + ((tB + (f) * 2048) ^ ((ks) * 64))))

#define QUADRANT(MB, BV, NB)                                                     \
    do {                                                                         \
        _Pragma("unroll") for (int ks = 0; ks < 2; ++ks)                         \
        _Pragma("unroll") for (int mf = 0; mf < 4; ++mf)                         \
        _Pragma("unroll") for (int nf = 0; nf < 2; ++nf)                         \
            acc[(MB) + mf][(NB) + nf] = __builtin_amdgcn_mfma_f32_16x16x32_bf16( \
                af[mf][ks], BV[nf][ks], acc[(MB) + mf][(NB) + nf], 0, 0, 0);     \
    } while (0)

#define PHASE_SYNC()                                  \
    __builtin_amdgcn_s_barrier();                     \
    asm volatile("s_waitcnt lgkmcnt(0)");             \
    __builtin_amdgcn_sched_barrier(0)

    // prologue: stage K-tile 0, drain once
    stage(0, 0); stage(0, 1); stage(0, 2); stage(0, 3);
    asm volatile("s_waitcnt vmcnt(0)" ::: "memory");
    __builtin_amdgcn_s_barrier();

    for (int T = 0; T < NT; ++T) {
        const int cur = T & 1;
        const bool pf = (T + 1 < NT);

        // ---- phase 1: A mf0-3 (8 reads) + B nf0-1 (4 reads); stage A0,B0 of T+1
#pragma unroll
        for (int f = 0; f < 4; ++f) { af[f][0] = RD_A(cur, f, 0); af[f][1] = RD_A(cur, f, 1); }
#pragma unroll
        for (int f = 0; f < 2; ++f) { b01[f][0] = RD_B(cur, f, 0); b01[f][1] = RD_B(cur, f, 1); }
        if (pf) { stage(T + 1, 0); stage(T + 1, 1); }
        PHASE_SYNC();
        __builtin_amdgcn_s_setprio(1);
        QUADRANT(0, b01, 0);
        __builtin_amdgcn_s_setprio(0);
        __builtin_amdgcn_s_barrier();

        // ---- phase 2: B nf2-3 (4 reads); stage A1,B1 of T+1
#pragma unroll
        for (int f = 0; f < 2; ++f) { b23[f][0] = RD_B(cur, f + 2, 0); b23[f][1] = RD_B(cur, f + 2, 1); }
        if (pf) { stage(T + 1, 2); stage(T + 1, 3); }
        PHASE_SYNC();
        __builtin_amdgcn_s_setprio(1);
        QUADRANT(0, b23, 2);
        __builtin_amdgcn_s_setprio(0);
        __builtin_amdgcn_s_barrier();

        // ---- phase 3: A mf4-7 (8 reads, overwrite af)
#pragma unroll
        for (int f = 0; f < 4; ++f) { af[f][0] = RD_A(cur, f + 4, 0); af[f][1] = RD_A(cur, f + 4, 1); }
        PHASE_SYNC();
        __builtin_amdgcn_s_setprio(1);
        QUADRANT(4, b23, 2);
        __builtin_amdgcn_s_setprio(0);
        __builtin_amdgcn_s_barrier();

        // ---- phase 4: no LDS reads (b01 still live); tile-boundary vmcnt drain.
        __builtin_amdgcn_s_setprio(1);
        QUADRANT(4, b01, 0);
        __builtin_amdgcn_s_setprio(0);
        if (pf) asm volatile("s_waitcnt vmcnt(0)" ::: "memory");   // T+1 staged in ph1/ph2
        __builtin_amdgcn_s_barrier();
    }

    // epilogue: C/D layout col=lane&15, row=quad*4+reg  [m89-verified]
#pragma unroll
    for (int nt = 0; nt < 4; ++nt) {
        int col = bn + wn * 64 + nt * 16 + l16;
        float bv = bias[col];
#pragma unroll
        for (int mt = 0; mt < 8; ++mt) {
            int row0 = bm + wm * 128 + mt * 16 + quad * 4;
#pragma unroll
            for (int r = 0; r < 4; ++r)
                C[(size_t)(row0 + r) * OUT_F + col] = acc[mt][nt][r] + bv;
        }
    }
#undef RD_A
#undef RD_B
#undef QUADRANT
#undef PHASE_SYNC
}

// ------------------------------------- fallback (no workspace): fp32 tiled GEMM
#define FBM 64
#define FBN 64
#define FBK 64
__global__ __launch_bounds__(256) void fallback_gemm(const float* __restrict__ x,
                                                     const int* __restrict__ q,
                                                     const float* __restrict__ sc,
                                                     const float* __restrict__ bias,
                                                     float* __restrict__ out) {
    __shared__ float sA[FBM][FBK + 1];
    __shared__ float sB[FBN][FBK + 1];
    const int tx = threadIdx.x & 15, ty = threadIdx.x >> 4;
    const int bm = blockIdx.y * FBM, bn = blockIdx.x * FBN;
    float acc[4][4] = {};
    for (int k0 = 0; k0 < IN_F; k0 += FBK) {
        for (int i = threadIdx.x; i < FBM * (FBK / 4); i += 256) {
            int r = i / (FBK / 4), c4 = (i % (FBK / 4)) * 4;
            float4 v = *(const float4*)&x[(size_t)(bm + r) * IN_F + k0 + c4];
            sA[r][c4] = v.x; sA[r][c4 + 1] = v.y; sA[r][c4 + 2] = v.z; sA[r][c4 + 3] = v.w;
            size_t fi = (size_t)(bn + r) * IN_F + k0 + c4;
            int4 qv = *(const int4*)&q[fi];
            float s = sc[fi >> 7];
            sB[r][c4]     = NF4_TAB[qv.x & 15] * s;
            sB[r][c4 + 1] = NF4_TAB[qv.y & 15] * s;
            sB[r][c4 + 2] = NF4_TAB[qv.z & 15] * s;
            sB[r][c4 + 3] = NF4_TAB[qv.w & 15] * s;
        }
        __syncthreads();
        for (int k = 0; k < FBK; ++k) {
            float av[4], bvv[4];
#pragma unroll
            for (int i = 0; i < 4; ++i) av[i] = sA[ty * 4 + i][k];
#pragma unroll
            for (int j = 0; j < 4; ++j) bvv[j] = sB[tx * 4 + j][k];
#pragma unroll
            for (int i = 0; i < 4; ++i)
#pragma unroll
                for (int j = 0; j < 4; ++j) acc[i][j] += av[i] * bvv[j];
        }
        __syncthreads();
    }
#pragma unroll
    for (int i = 0; i < 4; ++i)
#pragma unroll
        for (int j = 0; j < 4; ++j)
            out[(size_t)(bm + ty * 4 + i) * OUT_F + bn + tx * 4 + j] =
                acc[i][j] + bias[bn + tx * 4 + j];
}

// ---------------------------------------------------------------- launch
extern "C" void kernel_launch(void* const* d_in, const int* in_sizes, int n_in,
                              void* d_out, int out_size, void* d_ws, size_t ws_size,
                              hipStream_t stream) {
    const float* x    = (const float*)d_in[0];
    const int*   q    = (const int*)d_in[1];
    const float* sc   = (const float*)d_in[2];
    const float* bias = (const float*)d_in[3];
    float* out = (float*)d_out;

    const size_t xb_bytes = (size_t)M_ROWS * IN_F * sizeof(bf16);   // 67.1 MB
    const size_t wb_bytes = (size_t)OUT_F * IN_F * sizeof(bf16);    // 90.2 MB

    if (ws_size >= xb_bytes + wb_bytes) {
        bf16* xb = (bf16*)d_ws;
        bf16* wb = (bf16*)((char*)d_ws + xb_bytes);
        cvt_x_kernel<<<(M_ROWS * IN_F) / (8 * 256), 256, 0, stream>>>(x, xb);
        dequant_kernel<<<(OUT_F * IN_F) / (8 * 256), 256, 0, stream>>>(q, sc, wb);
        gemm_bias_kernel<<<GRID, 512, 0, stream>>>(xb, wb, bias, out);
    } else {
        fallback_gemm<<<dim3(OUT_F / FBN, M_ROWS / FBM), 256, 0, stream>>>(x, q, sc, bias, out);
    }
}